// Round 9
// baseline (1906.622 us; speedup 1.0000x reference)
//
#include <hip/hip_runtime.h>

#define NN 100000
#define DD 128
#define EE 600000
#define LNEPS 1e-5f

__device__ __forceinline__ float lrelu(float v) { return v > 0.f ? v : 0.2f * v; }

// ---------------- lin: f32 (round-1 verbatim, known-good)
__global__ __launch_bounds__(256) void lin_kernel(
    const float* __restrict__ x,
    const float* __restrict__ wl, const float* __restrict__ bl,
    const float* __restrict__ wr, const float* __restrict__ br,
    float* __restrict__ xl, float* __restrict__ xr)
{
    __shared__ __align__(16) float xs[64][128];
    const int tid  = threadIdx.x;
    const int row0 = blockIdx.x * 64;
#pragma unroll
    for (int i = 0; i < 32; ++i) {
        int idx = tid + i * 256;
        int r = idx >> 7, c = idx & 127;
        int row = row0 + r;
        xs[r][c] = (row < NN) ? x[(size_t)row * DD + c] : 0.f;
    }
    __syncthreads();
    const int cg = tid & 63;
    const int rg = tid >> 6;
    float acc[16][4];
    {
        float b0 = bl[cg], b1 = bl[cg + 64], b2 = br[cg], b3 = br[cg + 64];
#pragma unroll
        for (int r = 0; r < 16; ++r) { acc[r][0] = b0; acc[r][1] = b1; acc[r][2] = b2; acc[r][3] = b3; }
    }
    for (int k = 0; k < 128; k += 4) {
        float wa[4], wb[4], wc[4], wd[4];
#pragma unroll
        for (int i = 0; i < 4; ++i) {
            wa[i] = wl[(k + i) * DD + cg];
            wb[i] = wl[(k + i) * DD + cg + 64];
            wc[i] = wr[(k + i) * DD + cg];
            wd[i] = wr[(k + i) * DD + cg + 64];
        }
#pragma unroll
        for (int r = 0; r < 16; ++r) {
            float4 xv = *(const float4*)&xs[rg * 16 + r][k];
            acc[r][0] = fmaf(xv.x, wa[0], fmaf(xv.y, wa[1], fmaf(xv.z, wa[2], fmaf(xv.w, wa[3], acc[r][0]))));
            acc[r][1] = fmaf(xv.x, wb[0], fmaf(xv.y, wb[1], fmaf(xv.z, wb[2], fmaf(xv.w, wb[3], acc[r][1]))));
            acc[r][2] = fmaf(xv.x, wc[0], fmaf(xv.y, wc[1], fmaf(xv.z, wc[2], fmaf(xv.w, wc[3], acc[r][2]))));
            acc[r][3] = fmaf(xv.x, wd[0], fmaf(xv.y, wd[1], fmaf(xv.z, wd[2], fmaf(xv.w, wd[3], acc[r][3]))));
        }
    }
#pragma unroll
    for (int r = 0; r < 16; ++r) {
        int row = row0 + rg * 16 + r;
        if (row < NN) {
            xl[(size_t)row * DD + cg]      = acc[r][0];
            xl[(size_t)row * DD + cg + 64] = acc[r][1];
            xr[(size_t)row * DD + cg]      = acc[r][2];
            xr[(size_t)row * DD + cg + 64] = acc[r][3];
        }
    }
}

// ---------------- f32 weight transpose: out[n*K + k] = in[k*N + n]
__global__ __launch_bounds__(256) void transpose_kernel(
    const float* __restrict__ in, float* __restrict__ out, int K, int N)
{
    int t = blockIdx.x * 256 + threadIdx.x;
    if (t >= K * N) return;
    int k = t / N, n = t - k * N;          // t coalesced over n
    out[(size_t)n * K + k] = in[t];
}

// ---------------- CSR build ----------------
__global__ __launch_bounds__(256) void deg_hist_kernel(const int* __restrict__ ei, int* __restrict__ deg)
{
    int e = blockIdx.x * 256 + threadIdx.x;
    if (e < EE) atomicAdd(&deg[ei[EE + e]], 1);
}

__global__ __launch_bounds__(1024) void scan1_kernel(const int* __restrict__ deg,
                                                     int* __restrict__ rowstart,
                                                     int* __restrict__ partials)
{
    int gid = blockIdx.x * 1024 + threadIdx.x;
    int v = (gid < NN) ? deg[gid] : 0;
    int lane = threadIdx.x & 63, wid = threadIdx.x >> 6;
    int s = v;
#pragma unroll
    for (int o = 1; o < 64; o <<= 1) { int t = __shfl_up(s, o); if (lane >= o) s += t; }
    __shared__ int wsum[16];
    if (lane == 63) wsum[wid] = s;
    __syncthreads();
    if (wid == 0 && lane < 16) {
        int wv = wsum[lane];
        int ws = wv;
#pragma unroll
        for (int o = 1; o < 16; o <<= 1) { int t = __shfl_up(ws, o); if (lane >= o) ws += t; }
        wsum[lane] = ws - wv;
    }
    __syncthreads();
    int incl = s + wsum[wid];
    if (gid < NN) rowstart[gid] = incl - v;
    if (threadIdx.x == 1023) partials[blockIdx.x] = incl;
}

__global__ __launch_bounds__(128) void scan2_kernel(int* __restrict__ partials, int nb)
{
    int t = threadIdx.x;
    int v = (t < nb) ? partials[t] : 0;
    int lane = t & 63, wid = t >> 6;
    int s = v;
#pragma unroll
    for (int o = 1; o < 64; o <<= 1) { int tt = __shfl_up(s, o); if (lane >= o) s += tt; }
    __shared__ int wsum[2];
    if (lane == 63) wsum[wid] = s;
    __syncthreads();
    int add = (wid == 1) ? wsum[0] : 0;
    if (t < nb) partials[t] = s + add - v;
}

__global__ __launch_bounds__(1024) void scan3_kernel(int* __restrict__ rowstart, const int* __restrict__ partials)
{
    int gid = blockIdx.x * 1024 + threadIdx.x;
    if (gid < NN) rowstart[gid] += partials[blockIdx.x];
}

__global__ __launch_bounds__(256) void fill_kernel(const int* __restrict__ ei,
                                                   int* __restrict__ cursor,
                                                   int* __restrict__ esrc)
{
    int e = blockIdx.x * 256 + threadIdx.x;
    if (e >= EE) return;
    int dst = ei[EE + e];
    int pos = atomicAdd(&cursor[dst], 1);
    esrc[pos] = ei[e];
}

// ---------------- gather: per dst node, fused alpha + softmax + weighted sum
__global__ __launch_bounds__(256) void gather_kernel(
    const float* __restrict__ xl, const float* __restrict__ xr,
    const int* __restrict__ esrc,
    const int* __restrict__ rowstart, const int* __restrict__ rowend,
    const float* __restrict__ att,
    float* __restrict__ hout)
{
    int n = blockIdx.x * 4 + (threadIdx.x >> 6);
    if (n >= NN) return;
    int lane = threadIdx.x & 63;
    float2 xrv = *(const float2*)&xr[(size_t)n * DD + lane * 2];
    float2 av  = *(const float2*)&att[lane * 2];
    int s0 = rowstart[n], s1 = rowend[n];
    float accx = 0.f, accy = 0.f, denom = 0.f;
    for (int j = s0; j < s1; ++j) {
        int src = esrc[j];
        float2 xlv = *(const float2*)&xl[(size_t)src * DD + lane * 2];
        float p = lrelu(xlv.x + xrv.x) * av.x + lrelu(xlv.y + xrv.y) * av.y;
#pragma unroll
        for (int m = 1; m < 16; m <<= 1) p += __shfl_xor(p, m);
        float exv = __expf(p);     // max-shift skipped: |alpha| << 88, softmax identical
        denom += exv;
        accx = fmaf(exv, xlv.x, accx);
        accy = fmaf(exv, xlv.y, accy);
    }
    float inv = 1.f / (denom + 1e-16f);
    float2 o; o.x = accx * inv; o.y = accy * inv;
    *(float2*)&hout[(size_t)n * DD + lane * 2] = o;
}

// ---------------- fused f32 FFN + residual + LN, v2 (transposed weights, 40 KB LDS)
// h = hin + cbias ; out = LN(h + relu(h@W1+b1)@W2 + b2)
__global__ __launch_bounds__(256) void ffn_ln_f32v2_kernel(
    const float* __restrict__ hin, const float* __restrict__ cbias,
    const float* __restrict__ w1t, const float* __restrict__ b1,   // w1t: [512][128]
    const float* __restrict__ w2t, const float* __restrict__ b2,   // w2t: [128][512]
    const float* __restrict__ g, const float* __restrict__ bb,
    float* __restrict__ out)
{
    __shared__ __align__(16) float hrow[16][128];   // 8 KB
    __shared__ __align__(16) float T[16 * 512];     // 32 KB; reused as ybuf[16][132] after phase 2
    const int tid  = threadIdx.x;
    const int row0 = blockIdx.x * 16;               // N % 16 == 0
    // stage h = hin + cbias
#pragma unroll
    for (int i = 0; i < 8; ++i) {
        int idx = tid + i * 256;
        int r = idx >> 7, c = idx & 127;
        hrow[r][c] = hin[(size_t)(row0 + r) * DD + c] + cbias[c];
    }
    __syncthreads();
    // phase 1: T = relu(h @ W1 + b1); thread owns cols f, f+256 for all 16 rows
    {
        const int f = tid;
        float accA[16], accB[16];
        float bA = b1[f], bB = b1[f + 256];
#pragma unroll
        for (int r = 0; r < 16; ++r) { accA[r] = bA; accB[r] = bB; }
        for (int k = 0; k < 128; k += 4) {
            float4 wA = *(const float4*)&w1t[(size_t)f * 128 + k];
            float4 wB = *(const float4*)&w1t[(size_t)(f + 256) * 128 + k];
#pragma unroll
            for (int r = 0; r < 16; ++r) {
                float4 h = *(const float4*)&hrow[r][k];
                accA[r] = fmaf(h.x, wA.x, fmaf(h.y, wA.y, fmaf(h.z, wA.z, fmaf(h.w, wA.w, accA[r]))));
                accB[r] = fmaf(h.x, wB.x, fmaf(h.y, wB.y, fmaf(h.z, wB.z, fmaf(h.w, wB.w, accB[r]))));
            }
        }
#pragma unroll
        for (int r = 0; r < 16; ++r) {
            T[r * 512 + f]       = fmaxf(accA[r], 0.f);
            T[r * 512 + f + 256] = fmaxf(accB[r], 0.f);
        }
    }
    __syncthreads();
    // phase 2: Y = T @ W2; thread = (col d, k-half kh)
    {
        const int d  = tid & 127;
        const int kh = tid >> 7;
        float acc[16];
#pragma unroll
        for (int r = 0; r < 16; ++r) acc[r] = 0.f;
        const int k0 = kh * 256;
        for (int k = k0; k < k0 + 256; k += 4) {
            float4 wv = *(const float4*)&w2t[(size_t)d * 512 + k];
#pragma unroll
            for (int r = 0; r < 16; ++r) {
                float4 tv = *(const float4*)&T[r * 512 + k];
                acc[r] = fmaf(tv.x, wv.x, fmaf(tv.y, wv.y, fmaf(tv.z, wv.z, fmaf(tv.w, wv.w, acc[r]))));
            }
        }
        __syncthreads();            // all T reads complete -> reuse T as ybuf
        float* ybuf = T;            // [16][132] padded f32
        if (kh == 1) {
#pragma unroll
            for (int r = 0; r < 16; ++r) ybuf[r * 132 + d] = acc[r];
        }
        __syncthreads();
        if (kh == 0) {
            float bv = b2[d];
#pragma unroll
            for (int r = 0; r < 16; ++r)
                ybuf[r * 132 + d] = acc[r] + ybuf[r * 132 + d] + bv + hrow[r][d];
        }
    }
    __syncthreads();
    // LN epilogue (R2 numerics verbatim): wave w handles rows w, w+4, w+8, w+12
    {
        float* ybuf = T;
        const int wv = tid >> 6, lane = tid & 63;
        for (int r = wv; r < 16; r += 4) {
            float2 yv = *(const float2*)&ybuf[r * 132 + lane * 2];
            float s  = yv.x + yv.y;
            float s2 = yv.x * yv.x + yv.y * yv.y;
#pragma unroll
            for (int m = 1; m < 64; m <<= 1) { s += __shfl_xor(s, m); s2 += __shfl_xor(s2, m); }
            float mu  = s * (1.f / 128.f);
            float var = s2 * (1.f / 128.f) - mu * mu;
            float inv = rsqrtf(var + LNEPS);
            float2 gv = *(const float2*)&g[lane * 2];
            float2 bv = *(const float2*)&bb[lane * 2];
            float2 o;
            o.x = (yv.x - mu) * inv * gv.x + bv.x;
            o.y = (yv.y - mu) * inv * gv.y + bv.y;
            *(float2*)&out[(size_t)(row0 + r) * DD + lane * 2] = o;
        }
    }
}

extern "C" void kernel_launch(void* const* d_in, const int* in_sizes, int n_in,
                              void* d_out, int out_size, void* d_ws, size_t ws_size,
                              hipStream_t stream)
{
    const float* x       = (const float*)d_in[0];
    const int*   ei      = (const int*)d_in[1];
    const float* c1_wl   = (const float*)d_in[2];
    const float* c1_bl   = (const float*)d_in[3];
    const float* c1_wr   = (const float*)d_in[4];
    const float* c1_br   = (const float*)d_in[5];
    const float* c1_att  = (const float*)d_in[6];
    const float* c1_bias = (const float*)d_in[7];
    const float* c2_wl   = (const float*)d_in[8];
    const float* c2_bl   = (const float*)d_in[9];
    const float* c2_wr   = (const float*)d_in[10];
    const float* c2_br   = (const float*)d_in[11];
    const float* c2_att  = (const float*)d_in[12];
    const float* c2_bias = (const float*)d_in[13];
    const float* f1_w1   = (const float*)d_in[14];
    const float* f1_b1   = (const float*)d_in[15];
    const float* f1_w2   = (const float*)d_in[16];
    const float* f1_b2   = (const float*)d_in[17];
    const float* f2_w1   = (const float*)d_in[18];
    const float* f2_b1   = (const float*)d_in[19];
    const float* f2_w2   = (const float*)d_in[20];
    const float* f2_b2   = (const float*)d_in[21];
    const float* ln1_g   = (const float*)d_in[22];
    const float* ln1_b   = (const float*)d_in[23];
    const float* ln2_g   = (const float*)d_in[24];
    const float* ln2_b   = (const float*)d_in[25];

    float* out = (float*)d_out;
    float* ws  = (float*)d_ws;
    // ---- workspace: transposed f32 FFN weights (1 MB) | xl | xr | hacc | CSR (~157 MB total)
    float* f1w1t = ws;                   // 512*128
    float* f1w2t = f1w1t + 65536;        // 128*512
    float* f2w1t = f1w2t + 65536;
    float* f2w2t = f2w1t + 65536;
    float* xl    = f2w2t + 65536;
    float* xr    = xl + (size_t)NN * DD;
    float* hacc  = xr + (size_t)NN * DD;
    int* deg      = (int*)(hacc + (size_t)NN * DD);     // N
    int* rowstart = deg + NN;                           // N
    int* cursor   = rowstart + NN;                      // N
    int* partials = cursor + NN;                        // 128
    int* esrc     = partials + 128;                     // E

    const dim3 blk(256);
    const int linGrid    = (NN + 63) / 64;
    const int edgeGrid   = (EE + 255) / 256;
    const int gatherGrid = (NN + 3) / 4;
    const int ffnGrid    = NN / 16;
    const int scanBlocks = (NN + 1023) / 1024;
    const int trGrid     = (128 * 512 + 255) / 256;     // 256

    // ---------- CSR build ----------
    hipMemsetAsync(deg, 0, (size_t)NN * sizeof(int), stream);
    deg_hist_kernel<<<edgeGrid, blk, 0, stream>>>(ei, deg);
    scan1_kernel<<<scanBlocks, 1024, 0, stream>>>(deg, rowstart, partials);
    scan2_kernel<<<1, 128, 0, stream>>>(partials, scanBlocks);
    scan3_kernel<<<scanBlocks, 1024, 0, stream>>>(rowstart, partials);
    hipMemcpyAsync(cursor, rowstart, (size_t)NN * sizeof(int), hipMemcpyDeviceToDevice, stream);
    fill_kernel<<<edgeGrid, blk, 0, stream>>>(ei, cursor, esrc);

    // ---------- f32 weight transposes ----------
    transpose_kernel<<<trGrid, blk, 0, stream>>>(f1_w1, f1w1t, 128, 512);
    transpose_kernel<<<trGrid, blk, 0, stream>>>(f1_w2, f1w2t, 512, 128);
    transpose_kernel<<<trGrid, blk, 0, stream>>>(f2_w1, f2w1t, 128, 512);
    transpose_kernel<<<trGrid, blk, 0, stream>>>(f2_w2, f2w2t, 512, 128);

    // ---------- layer 1 ----------
    lin_kernel<<<linGrid, blk, 0, stream>>>(x, c1_wl, c1_bl, c1_wr, c1_br, xl, xr);
    gather_kernel<<<gatherGrid, blk, 0, stream>>>(xl, xr, esrc, rowstart, cursor, c1_att, hacc);
    ffn_ln_f32v2_kernel<<<ffnGrid, blk, 0, stream>>>(hacc, c1_bias, f1w1t, f1_b1, f1w2t, f1_b2,
                                                     ln1_g, ln1_b, out);
    // ---------- layer 2 ----------
    lin_kernel<<<linGrid, blk, 0, stream>>>(out, c2_wl, c2_bl, c2_wr, c2_br, xl, xr);
    gather_kernel<<<gatherGrid, blk, 0, stream>>>(xl, xr, esrc, rowstart, cursor, c2_att, hacc);
    ffn_ln_f32v2_kernel<<<ffnGrid, blk, 0, stream>>>(hacc, c2_bias, f2w1t, f2_b1, f2w2t, f2_b2,
                                                     ln2_g, ln2_b, out);
}

// Round 10
// 1445.922 us; speedup vs baseline: 1.3186x; 1.3186x over previous
//
#include <hip/hip_runtime.h>

#define NN 100000
#define DD 128
#define EE 600000
#define LNEPS 1e-5f

__device__ __forceinline__ float lrelu(float v) { return v > 0.f ? v : 0.2f * v; }

// ---------------- lin: f32 (round-1 verbatim, known-good)
__global__ __launch_bounds__(256) void lin_kernel(
    const float* __restrict__ x,
    const float* __restrict__ wl, const float* __restrict__ bl,
    const float* __restrict__ wr, const float* __restrict__ br,
    float* __restrict__ xl, float* __restrict__ xr)
{
    __shared__ __align__(16) float xs[64][128];
    const int tid  = threadIdx.x;
    const int row0 = blockIdx.x * 64;
#pragma unroll
    for (int i = 0; i < 32; ++i) {
        int idx = tid + i * 256;
        int r = idx >> 7, c = idx & 127;
        int row = row0 + r;
        xs[r][c] = (row < NN) ? x[(size_t)row * DD + c] : 0.f;
    }
    __syncthreads();
    const int cg = tid & 63;
    const int rg = tid >> 6;
    float acc[16][4];
    {
        float b0 = bl[cg], b1 = bl[cg + 64], b2 = br[cg], b3 = br[cg + 64];
#pragma unroll
        for (int r = 0; r < 16; ++r) { acc[r][0] = b0; acc[r][1] = b1; acc[r][2] = b2; acc[r][3] = b3; }
    }
    for (int k = 0; k < 128; k += 4) {
        float wa[4], wb[4], wc[4], wd[4];
#pragma unroll
        for (int i = 0; i < 4; ++i) {
            wa[i] = wl[(k + i) * DD + cg];
            wb[i] = wl[(k + i) * DD + cg + 64];
            wc[i] = wr[(k + i) * DD + cg];
            wd[i] = wr[(k + i) * DD + cg + 64];
        }
#pragma unroll
        for (int r = 0; r < 16; ++r) {
            float4 xv = *(const float4*)&xs[rg * 16 + r][k];
            acc[r][0] = fmaf(xv.x, wa[0], fmaf(xv.y, wa[1], fmaf(xv.z, wa[2], fmaf(xv.w, wa[3], acc[r][0]))));
            acc[r][1] = fmaf(xv.x, wb[0], fmaf(xv.y, wb[1], fmaf(xv.z, wb[2], fmaf(xv.w, wb[3], acc[r][1]))));
            acc[r][2] = fmaf(xv.x, wc[0], fmaf(xv.y, wc[1], fmaf(xv.z, wc[2], fmaf(xv.w, wc[3], acc[r][2]))));
            acc[r][3] = fmaf(xv.x, wd[0], fmaf(xv.y, wd[1], fmaf(xv.z, wd[2], fmaf(xv.w, wd[3], acc[r][3]))));
        }
    }
#pragma unroll
    for (int r = 0; r < 16; ++r) {
        int row = row0 + rg * 16 + r;
        if (row < NN) {
            xl[(size_t)row * DD + cg]      = acc[r][0];
            xl[(size_t)row * DD + cg + 64] = acc[r][1];
            xr[(size_t)row * DD + cg]      = acc[r][2];
            xr[(size_t)row * DD + cg + 64] = acc[r][3];
        }
    }
}

// ---------------- CSR build ----------------
__global__ __launch_bounds__(256) void deg_hist_kernel(const int* __restrict__ ei, int* __restrict__ deg)
{
    int e = blockIdx.x * 256 + threadIdx.x;
    if (e < EE) atomicAdd(&deg[ei[EE + e]], 1);
}

__global__ __launch_bounds__(1024) void scan1_kernel(const int* __restrict__ deg,
                                                     int* __restrict__ rowstart,
                                                     int* __restrict__ partials)
{
    int gid = blockIdx.x * 1024 + threadIdx.x;
    int v = (gid < NN) ? deg[gid] : 0;
    int lane = threadIdx.x & 63, wid = threadIdx.x >> 6;
    int s = v;
#pragma unroll
    for (int o = 1; o < 64; o <<= 1) { int t = __shfl_up(s, o); if (lane >= o) s += t; }
    __shared__ int wsum[16];
    if (lane == 63) wsum[wid] = s;
    __syncthreads();
    if (wid == 0 && lane < 16) {
        int wv = wsum[lane];
        int ws = wv;
#pragma unroll
        for (int o = 1; o < 16; o <<= 1) { int t = __shfl_up(ws, o); if (lane >= o) ws += t; }
        wsum[lane] = ws - wv;
    }
    __syncthreads();
    int incl = s + wsum[wid];
    if (gid < NN) rowstart[gid] = incl - v;
    if (threadIdx.x == 1023) partials[blockIdx.x] = incl;
}

__global__ __launch_bounds__(128) void scan2_kernel(int* __restrict__ partials, int nb)
{
    int t = threadIdx.x;
    int v = (t < nb) ? partials[t] : 0;
    int lane = t & 63, wid = t >> 6;
    int s = v;
#pragma unroll
    for (int o = 1; o < 64; o <<= 1) { int tt = __shfl_up(s, o); if (lane >= o) s += tt; }
    __shared__ int wsum[2];
    if (lane == 63) wsum[wid] = s;
    __syncthreads();
    int add = (wid == 1) ? wsum[0] : 0;
    if (t < nb) partials[t] = s + add - v;
}

__global__ __launch_bounds__(1024) void scan3_kernel(int* __restrict__ rowstart, const int* __restrict__ partials)
{
    int gid = blockIdx.x * 1024 + threadIdx.x;
    if (gid < NN) rowstart[gid] += partials[blockIdx.x];
}

__global__ __launch_bounds__(256) void fill_kernel(const int* __restrict__ ei,
                                                   int* __restrict__ cursor,
                                                   int* __restrict__ esrc)
{
    int e = blockIdx.x * 256 + threadIdx.x;
    if (e >= EE) return;
    int dst = ei[EE + e];
    int pos = atomicAdd(&cursor[dst], 1);
    esrc[pos] = ei[e];
}

// ---------------- gather: per dst node, fused alpha + softmax + weighted sum
__global__ __launch_bounds__(256) void gather_kernel(
    const float* __restrict__ xl, const float* __restrict__ xr,
    const int* __restrict__ esrc,
    const int* __restrict__ rowstart, const int* __restrict__ rowend,
    const float* __restrict__ att,
    float* __restrict__ hout)
{
    int n = blockIdx.x * 4 + (threadIdx.x >> 6);
    if (n >= NN) return;
    int lane = threadIdx.x & 63;
    float2 xrv = *(const float2*)&xr[(size_t)n * DD + lane * 2];
    float2 av  = *(const float2*)&att[lane * 2];
    int s0 = rowstart[n], s1 = rowend[n];
    float accx = 0.f, accy = 0.f, denom = 0.f;
    for (int j = s0; j < s1; ++j) {
        int src = esrc[j];
        float2 xlv = *(const float2*)&xl[(size_t)src * DD + lane * 2];
        float p = lrelu(xlv.x + xrv.x) * av.x + lrelu(xlv.y + xrv.y) * av.y;
#pragma unroll
        for (int m = 1; m < 16; m <<= 1) p += __shfl_xor(p, m);
        float exv = __expf(p);     // max-shift skipped: |alpha| << 88, softmax identical
        denom += exv;
        accx = fmaf(exv, xlv.x, accx);
        accy = fmaf(exv, xlv.y, accy);
    }
    float inv = 1.f / (denom + 1e-16f);
    float2 o; o.x = accx * inv; o.y = accy * inv;
    *(float2*)&hout[(size_t)n * DD + lane * 2] = o;
}

// ---------------- fused f32 FFN + residual + LN, v3
// LDS-read amortization: 1 broadcast ds_read_b128 per 16 FMAs in both phases;
// weight loads stay scalar lane-coalesced (R8 lesson: never per-lane strided float4).
// h = hin + cbias ; out = LN(h + relu(h@W1+b1)@W2 + b2)
__global__ __launch_bounds__(256) void ffn_ln_f32v3_kernel(
    const float* __restrict__ hin, const float* __restrict__ cbias,
    const float* __restrict__ w1, const float* __restrict__ b1,   // w1: [128][512]
    const float* __restrict__ w2, const float* __restrict__ b2,   // w2: [512][128]
    const float* __restrict__ g, const float* __restrict__ bb,
    float* __restrict__ out)
{
    __shared__ __align__(16) float hrow[16][128];   // 8 KB
    __shared__ __align__(16) float T[16 * 512];     // 32 KB; reused as ybuf[16][132] after phase 2
    const int tid  = threadIdx.x;
    const int row0 = blockIdx.x * 16;               // N % 16 == 0
    // stage h = hin + cbias
#pragma unroll
    for (int i = 0; i < 8; ++i) {
        int idx = tid + i * 256;
        int r = idx >> 7, c = idx & 127;
        hrow[r][c] = hin[(size_t)(row0 + r) * DD + c] + cbias[c];
    }
    __syncthreads();
    // phase 1: T = relu(h @ W1 + b1)
    // thread = (rg = tid>>7 in [0,2), c4 = tid&127): rows rg*8..+8, cols c4+128j (j=0..3)
    {
        const int rg = tid >> 7, c4 = tid & 127;
        float bv[4];
#pragma unroll
        for (int j = 0; j < 4; ++j) bv[j] = b1[c4 + 128 * j];
        float acc[8][4];
#pragma unroll
        for (int r = 0; r < 8; ++r)
#pragma unroll
            for (int j = 0; j < 4; ++j) acc[r][j] = bv[j];
        for (int k = 0; k < 128; k += 4) {
            float wv[4][4];
#pragma unroll
            for (int i = 0; i < 4; ++i)
#pragma unroll
                for (int j = 0; j < 4; ++j)
                    wv[i][j] = w1[(size_t)(k + i) * 512 + c4 + 128 * j];
#pragma unroll
            for (int r = 0; r < 8; ++r) {
                float4 h = *(const float4*)&hrow[rg * 8 + r][k];   // wave-uniform -> broadcast
#pragma unroll
                for (int j = 0; j < 4; ++j)
                    acc[r][j] = fmaf(h.x, wv[0][j], fmaf(h.y, wv[1][j],
                                fmaf(h.z, wv[2][j], fmaf(h.w, wv[3][j], acc[r][j]))));
            }
        }
#pragma unroll
        for (int r = 0; r < 8; ++r)
#pragma unroll
            for (int j = 0; j < 4; ++j)
                T[(rg * 8 + r) * 512 + c4 + 128 * j] = fmaxf(acc[r][j], 0.f);
    }
    __syncthreads();
    // phase 2: Y = T @ W2 (+b2 +residual)
    // thread = (rg = tid>>5 in [0,8), c = tid&31): rows rg*2..+2, cols c+32j (j=0..3)
    {
        const int rg = tid >> 5, c = tid & 31;
        float acc[2][4];
#pragma unroll
        for (int r = 0; r < 2; ++r)
#pragma unroll
            for (int j = 0; j < 4; ++j) acc[r][j] = 0.f;
        for (int k = 0; k < 512; k += 4) {
            float wv[4][4];
#pragma unroll
            for (int i = 0; i < 4; ++i)
#pragma unroll
                for (int j = 0; j < 4; ++j)
                    wv[i][j] = w2[(size_t)(k + i) * 128 + c + 32 * j];
#pragma unroll
            for (int r = 0; r < 2; ++r) {
                float4 t = *(const float4*)&T[(rg * 2 + r) * 512 + k];   // 2 addrs/wave -> free
#pragma unroll
                for (int j = 0; j < 4; ++j)
                    acc[r][j] = fmaf(t.x, wv[0][j], fmaf(t.y, wv[1][j],
                                fmaf(t.z, wv[2][j], fmaf(t.w, wv[3][j], acc[r][j]))));
            }
        }
        __syncthreads();            // all T reads complete -> reuse T as ybuf
        float* ybuf = T;            // [16][132] padded f32
#pragma unroll
        for (int r = 0; r < 2; ++r)
#pragma unroll
            for (int j = 0; j < 4; ++j) {
                int row = rg * 2 + r, col = c + 32 * j;
                ybuf[row * 132 + col] = acc[r][j] + b2[col] + hrow[row][col];
            }
    }
    __syncthreads();
    // LN epilogue (R2 numerics verbatim): wave w handles rows w, w+4, w+8, w+12
    {
        float* ybuf = T;
        const int wv = tid >> 6, lane = tid & 63;
        for (int r = wv; r < 16; r += 4) {
            float2 yv = *(const float2*)&ybuf[r * 132 + lane * 2];
            float s  = yv.x + yv.y;
            float s2 = yv.x * yv.x + yv.y * yv.y;
#pragma unroll
            for (int m = 1; m < 64; m <<= 1) { s += __shfl_xor(s, m); s2 += __shfl_xor(s2, m); }
            float mu  = s * (1.f / 128.f);
            float var = s2 * (1.f / 128.f) - mu * mu;
            float inv = rsqrtf(var + LNEPS);
            float2 gv = *(const float2*)&g[lane * 2];
            float2 bv = *(const float2*)&bb[lane * 2];
            float2 o;
            o.x = (yv.x - mu) * inv * gv.x + bv.x;
            o.y = (yv.y - mu) * inv * gv.y + bv.y;
            *(float2*)&out[(size_t)(row0 + r) * DD + lane * 2] = o;
        }
    }
}

extern "C" void kernel_launch(void* const* d_in, const int* in_sizes, int n_in,
                              void* d_out, int out_size, void* d_ws, size_t ws_size,
                              hipStream_t stream)
{
    const float* x       = (const float*)d_in[0];
    const int*   ei      = (const int*)d_in[1];
    const float* c1_wl   = (const float*)d_in[2];
    const float* c1_bl   = (const float*)d_in[3];
    const float* c1_wr   = (const float*)d_in[4];
    const float* c1_br   = (const float*)d_in[5];
    const float* c1_att  = (const float*)d_in[6];
    const float* c1_bias = (const float*)d_in[7];
    const float* c2_wl   = (const float*)d_in[8];
    const float* c2_bl   = (const float*)d_in[9];
    const float* c2_wr   = (const float*)d_in[10];
    const float* c2_br   = (const float*)d_in[11];
    const float* c2_att  = (const float*)d_in[12];
    const float* c2_bias = (const float*)d_in[13];
    const float* f1_w1   = (const float*)d_in[14];
    const float* f1_b1   = (const float*)d_in[15];
    const float* f1_w2   = (const float*)d_in[16];
    const float* f1_b2   = (const float*)d_in[17];
    const float* f2_w1   = (const float*)d_in[18];
    const float* f2_b1   = (const float*)d_in[19];
    const float* f2_w2   = (const float*)d_in[20];
    const float* f2_b2   = (const float*)d_in[21];
    const float* ln1_g   = (const float*)d_in[22];
    const float* ln1_b   = (const float*)d_in[23];
    const float* ln2_g   = (const float*)d_in[24];
    const float* ln2_b   = (const float*)d_in[25];

    float* out = (float*)d_out;
    float* ws  = (float*)d_ws;
    float* xl    = ws;                                  // N*128 f32
    float* xr    = xl   + (size_t)NN * DD;
    float* hacc  = xr   + (size_t)NN * DD;
    int* deg      = (int*)(hacc + (size_t)NN * DD);     // N
    int* rowstart = deg + NN;                           // N
    int* cursor   = rowstart + NN;                      // N
    int* partials = cursor + NN;                        // 128
    int* esrc     = partials + 128;                     // E

    const dim3 blk(256);
    const int linGrid    = (NN + 63) / 64;
    const int edgeGrid   = (EE + 255) / 256;
    const int gatherGrid = (NN + 3) / 4;
    const int ffnGrid    = NN / 16;
    const int scanBlocks = (NN + 1023) / 1024;

    // ---------- CSR build ----------
    hipMemsetAsync(deg, 0, (size_t)NN * sizeof(int), stream);
    deg_hist_kernel<<<edgeGrid, blk, 0, stream>>>(ei, deg);
    scan1_kernel<<<scanBlocks, 1024, 0, stream>>>(deg, rowstart, partials);
    scan2_kernel<<<1, 128, 0, stream>>>(partials, scanBlocks);
    scan3_kernel<<<scanBlocks, 1024, 0, stream>>>(rowstart, partials);
    hipMemcpyAsync(cursor, rowstart, (size_t)NN * sizeof(int), hipMemcpyDeviceToDevice, stream);
    fill_kernel<<<edgeGrid, blk, 0, stream>>>(ei, cursor, esrc);

    // ---------- layer 1 ----------
    lin_kernel<<<linGrid, blk, 0, stream>>>(x, c1_wl, c1_bl, c1_wr, c1_br, xl, xr);
    gather_kernel<<<gatherGrid, blk, 0, stream>>>(xl, xr, esrc, rowstart, cursor, c1_att, hacc);
    ffn_ln_f32v3_kernel<<<ffnGrid, blk, 0, stream>>>(hacc, c1_bias, f1_w1, f1_b1, f1_w2, f1_b2,
                                                     ln1_g, ln1_b, out);
    // ---------- layer 2 ----------
    lin_kernel<<<linGrid, blk, 0, stream>>>(out, c2_wl, c2_bl, c2_wr, c2_br, xl, xr);
    gather_kernel<<<gatherGrid, blk, 0, stream>>>(xl, xr, esrc, rowstart, cursor, c2_att, hacc);
    ffn_ln_f32v3_kernel<<<ffnGrid, blk, 0, stream>>>(hacc, c2_bias, f2_w1, f2_b1, f2_w2, f2_b2,
                                                     ln2_g, ln2_b, out);
}